// Round 3
// baseline (553.219 us; speedup 1.0000x reference)
//
#include <hip/hip_runtime.h>

// Problem dims (fixed by reference)
#define Bdim 16
#define Sdim 128
#define Mdim 128
#define Ddim 256              // emb dim
#define Hdim 256              // hidden dim
#define NNODE (Bdim * Sdim)   // 2048 nodes
#define KK (2 * Ddim)         // 512 = GEMM K

// ---------------- Kernel A: streaming masked reduction ----------------
// 512 blocks x 256 threads (4 waves), 4 nodes per block processed
// sequentially. Waves interleave 8-row batches so each block sweeps only
// TWO moving address windows (src, neigh) -> ~1024 device-wide streams
// instead of ~4096. 16 float4 loads in flight per wave (16 KiB).
#define A_GRID 512
#define A_NPB (NNODE / A_GRID)   // 4

__global__ __launch_bounds__(256, 2) void gcn_reduce(
    const float* __restrict__ src,
    const float* __restrict__ neigh,
    float* __restrict__ hidden)          // [NNODE][KK] in d_ws
{
    const int tid  = threadIdx.x;
    const int wave = tid >> 6;           // 0..3
    const int lane = tid & 63;

    __shared__ float s_s[4][Ddim];
    __shared__ float s_n[4][Ddim];
    __shared__ int   s_cnt[4];

    for (int ln = 0; ln < A_NPB; ++ln) {
        const int node = blockIdx.x * A_NPB + ln;
        const float4* __restrict__ src4 =
            (const float4*)src + (size_t)node * (Mdim * Ddim / 4);
        const float4* __restrict__ ngh4 =
            (const float4*)neigh + (size_t)node * (Mdim * Ddim / 4);

        float4 sacc = make_float4(0.f, 0.f, 0.f, 0.f);
        float4 nacc = make_float4(0.f, 0.f, 0.f, 0.f);
        int cnt = 0;

        // 16 batches of 8 contiguous rows; wave w takes batches b ≡ w (mod 4).
        // One wave-load = 64 lanes * 16B = one full 256-col row (1 KiB), so
        // __any() over the wave gives the row's any(!=0) bit exactly.
        for (int b = wave; b < 16; b += 4) {
            const int m0 = b * 8;
            float4 sv[8], nv[8];
            #pragma unroll
            for (int j = 0; j < 8; ++j)
                sv[j] = src4[(m0 + j) * (Ddim / 4) + lane];
            #pragma unroll
            for (int j = 0; j < 8; ++j)
                nv[j] = ngh4[(m0 + j) * (Ddim / 4) + lane];
            #pragma unroll
            for (int j = 0; j < 8; ++j) {
                sacc.x += sv[j].x; sacc.y += sv[j].y;
                sacc.z += sv[j].z; sacc.w += sv[j].w;
                nacc.x += nv[j].x; nacc.y += nv[j].y;
                nacc.z += nv[j].z; nacc.w += nv[j].w;
                int nz = (nv[j].x != 0.f) | (nv[j].y != 0.f) |
                         (nv[j].z != 0.f) | (nv[j].w != 0.f);
                if (__any(nz)) cnt++;
            }
        }

        *(float4*)&s_s[wave][lane * 4] = sacc;
        *(float4*)&s_n[wave][lane * 4] = nacc;
        if (lane == 0) s_cnt[wave] = cnt;
        __syncthreads();

        {
            const float num = (float)(s_cnt[0] + s_cnt[1] + s_cnt[2] + s_cnt[3]);
            const float inv = 1.0f / fmaxf(num, 1.0f);
            const float ss = s_s[0][tid] + s_s[1][tid] + s_s[2][tid] + s_s[3][tid];
            const float ns = s_n[0][tid] + s_n[1][tid] + s_n[2][tid] + s_n[3][tid];
            hidden[(size_t)node * KK + tid]        = ss;        // concat: src-sum
            hidden[(size_t)node * KK + Ddim + tid] = ns * inv;  // neigh-mean
        }
        __syncthreads();   // LDS reused by next node
    }
}

// ---------------- Kernel B: [2048,512] x [512,256] + bias + leaky ----------------
// 256 blocks x 512 threads. Block handles 8 output rows; half-block (256 thr)
// handles 4 rows, thread t owns column t. hidden[row][k] is wave-uniform ->
// scalar (s_load) broadcasts; W read once per block, coalesced.
#define B_GRID 256

__global__ __launch_bounds__(512, 2) void gcn_gemm(
    const float* __restrict__ hidden,    // [NNODE][KK]
    const float* __restrict__ Wmap,      // [KK][Hdim] row-major
    const float* __restrict__ bmap,      // [Hdim]
    float* __restrict__ out)             // [NNODE][Hdim]
{
    const int t    = threadIdx.x & (Hdim - 1);
    const int half = threadIdx.x >> 8;           // 0 or 1 (wave-uniform)
    const int r0   = blockIdx.x * 8 + half * 4;  // first of 4 rows

    const float* __restrict__ h = hidden + (size_t)r0 * KK;

    const float bv = bmap[t];
    float acc0 = bv, acc1 = bv, acc2 = bv, acc3 = bv;

    #pragma unroll 8
    for (int k = 0; k < KK; ++k) {
        const float wv = Wmap[(size_t)k * Hdim + t];   // coalesced, L1/L2-hot
        acc0 = fmaf(h[k],          wv, acc0);          // uniform -> s_load
        acc1 = fmaf(h[KK + k],     wv, acc1);
        acc2 = fmaf(h[2 * KK + k], wv, acc2);
        acc3 = fmaf(h[3 * KK + k], wv, acc3);
    }

    const float r0v = acc0 > 0.f ? acc0 : 0.01f * acc0;
    const float r1v = acc1 > 0.f ? acc1 : 0.01f * acc1;
    const float r2v = acc2 > 0.f ? acc2 : 0.01f * acc2;
    const float r3v = acc3 > 0.f ? acc3 : 0.01f * acc3;
    out[(size_t)(r0 + 0) * Hdim + t] = r0v;
    out[(size_t)(r0 + 1) * Hdim + t] = r1v;
    out[(size_t)(r0 + 2) * Hdim + t] = r2v;
    out[(size_t)(r0 + 3) * Hdim + t] = r3v;
}

extern "C" void kernel_launch(void* const* d_in, const int* in_sizes, int n_in,
                              void* d_out, int out_size, void* d_ws, size_t ws_size,
                              hipStream_t stream) {
    const float* src   = (const float*)d_in[0];
    const float* neigh = (const float*)d_in[1];
    const float* Wmap  = (const float*)d_in[2];
    const float* bmap  = (const float*)d_in[3];
    float* out    = (float*)d_out;
    float* hidden = (float*)d_ws;        // needs NNODE*KK*4 = 4 MiB of ws

    gcn_reduce<<<dim3(A_GRID), dim3(256), 0, stream>>>(src, neigh, hidden);
    gcn_gemm<<<dim3(B_GRID), dim3(512), 0, stream>>>(hidden, Wmap, bmap, out);
}